// Round 1
// baseline (861.582 us; speedup 1.0000x reference)
//
#include <hip/hip_runtime.h>

#define T_LEN 256
#define D_IN 4
#define HID 16

struct CellW { const float *Wih, *Whh, *bih, *bhh; };
struct Params { CellW c[6]; const float* y; float* hout; };

__device__ __forceinline__ float rl(float v, int l) {
    return __int_as_float(__builtin_amdgcn_readlane(__float_as_int(v), l));
}

template<int Q>
__device__ __forceinline__ float qb(float v) {
    // broadcast lane Q of each quad to all 4 lanes of the quad (DPP quad_perm)
    return __int_as_float(__builtin_amdgcn_update_dpp(
        0, __float_as_int(v), Q * 0x55, 0xF, 0xF, true));
}

__device__ __forceinline__ float fexp2(float x) { return __builtin_amdgcn_exp2f(x); }
__device__ __forceinline__ float frcp(float x)  { return __builtin_amdgcn_rcpf(x); }

// tanh(c) = 1 - 2/(exp2(2*log2e*c)+1); inf-safe at both ends
__device__ __forceinline__ float ftanh(float c) {
    float e = fexp2(c * 2.8853900817779268f);
    return fmaf(-2.f, frcp(1.f + e), 1.f);
}

template<int NIN>
__device__ __forceinline__ void cell_step(
    const float (&sin_)[NIN], const float (&shh)[HID],
    const float (&wih)[NIN], const float (&whh)[HID], float bias,
    float kmul, float rmul, float radd,
    float& c, float& h)
{
    float a0 = bias, a1 = 0.f;
#pragma unroll
    for (int k = 0; k < NIN; k += 2) {
        a0 = fmaf(sin_[k],   wih[k],   a0);
        a1 = fmaf(sin_[k+1], wih[k+1], a1);
    }
#pragma unroll
    for (int k = 0; k < HID; k += 2) {
        a0 = fmaf(shh[k],   whh[k],   a0);
        a1 = fmaf(shh[k+1], whh[k+1], a1);
    }
    float x = a0 + a1;
    // unified activation: sigmoid for i,f,o lanes; tanh for g lanes
    float e = fexp2(x * kmul);
    float s = frcp(1.f + e);
    float act = fmaf(rmul, s, radd);
    // gather i,f,g,o within the quad (pure-VALU DPP)
    float gi = qb<0>(act);
    float gf = qb<1>(act);
    float gg = qb<2>(act);
    float go = qb<3>(act);
    c = fmaf(gf, c, gi * gg);
    h = go * ftanh(c);
}

__global__ void __launch_bounds__(256)
lstm_chain_kernel(Params p)
{
    const int lane = threadIdx.x & 63;
    const int wid  = blockIdx.x * (blockDim.x >> 6) + (threadIdx.x >> 6);
    const int b    = wid >> 1;
    const int dir  = wid & 1;
    const int j    = lane >> 2;   // hidden unit
    const int g    = lane & 3;    // gate: 0=i 1=f 2=g 3=o
    const int r    = g * HID + j; // gate row in [64, *] weight matrices

    const CellW c1 = p.c[dir * 3 + 0];
    const CellW c2 = p.c[dir * 3 + 1];
    const CellW c3 = p.c[dir * 3 + 2];

    // ---- per-lane weights into registers (loaded once; 46KB total -> L2-hot) ----
    float wih1[D_IN], whh1[HID], wih2[HID], whh2[HID], wih3[HID], whh3[HID];
    {
        float4 t = *(const float4*)(c1.Wih + r * D_IN);
        wih1[0] = t.x; wih1[1] = t.y; wih1[2] = t.z; wih1[3] = t.w;
    }
#pragma unroll
    for (int k = 0; k < HID; k += 4) {
        float4 a = *(const float4*)(c1.Whh + r * HID + k);
        whh1[k] = a.x; whh1[k+1] = a.y; whh1[k+2] = a.z; whh1[k+3] = a.w;
        float4 bwi = *(const float4*)(c2.Wih + r * HID + k);
        wih2[k] = bwi.x; wih2[k+1] = bwi.y; wih2[k+2] = bwi.z; wih2[k+3] = bwi.w;
        float4 bh = *(const float4*)(c2.Whh + r * HID + k);
        whh2[k] = bh.x; whh2[k+1] = bh.y; whh2[k+2] = bh.z; whh2[k+3] = bh.w;
        float4 cwi = *(const float4*)(c3.Wih + r * HID + k);
        wih3[k] = cwi.x; wih3[k+1] = cwi.y; wih3[k+2] = cwi.z; wih3[k+3] = cwi.w;
        float4 ch = *(const float4*)(c3.Whh + r * HID + k);
        whh3[k] = ch.x; whh3[k+1] = ch.y; whh3[k+2] = ch.z; whh3[k+3] = ch.w;
    }
    const float bias1 = c1.bih[r] + c1.bhh[r];
    const float bias2 = c2.bih[r] + c2.bhh[r];
    const float bias3 = c3.bih[r] + c3.bhh[r];

    // per-lane activation constants (g-gate lanes do tanh = 2*sigmoid(2x)-1)
    const bool  isg  = (g == 2);
    const float kmul = isg ? -2.8853900817779268f : -1.4426950408889634f;
    const float rmul = isg ? 2.f : 1.f;
    const float radd = isg ? -1.f : 0.f;

    // state
    float cc1 = 0.f, cc2 = 0.f, cc3 = 0.f;
    float h1 = 0.f, h2 = 0.f, h3 = 0.f;
    float sh1[HID], sh2[HID], sh3[HID];
#pragma unroll
    for (int k = 0; k < HID; ++k) { sh1[k] = 0.f; sh2[k] = 0.f; sh3[k] = 0.f; }

    const float* ybase = p.y + (size_t)b * (T_LEN * D_IN);

#pragma unroll 1
    for (int t = 0; t < T_LEN; ++t) {
        const int tt = dir ? (T_LEN - 1 - t) : t;
        const float4 xv = *(const float4*)(ybase + tt * D_IN);
        float sx[D_IN] = {xv.x, xv.y, xv.z, xv.w};

        cell_step<D_IN>(sx, sh1, wih1, whh1, bias1, kmul, rmul, radd, cc1, h1);
#pragma unroll
        for (int k = 0; k < HID; ++k) sh1[k] = rl(h1, 4 * k);

        cell_step<HID>(sh1, sh2, wih2, whh2, bias2, kmul, rmul, radd, cc2, h2);
#pragma unroll
        for (int k = 0; k < HID; ++k) sh2[k] = rl(h2, 4 * k);

        cell_step<HID>(sh2, sh3, wih3, whh3, bias3, kmul, rmul, radd, cc3, h3);
#pragma unroll
        for (int k = 0; k < HID; ++k) sh3[k] = rl(h3, 4 * k);
    }

    if (g == 0) p.hout[(size_t)b * 32 + dir * HID + j] = h3;
}

__global__ void out_proj_kernel(const float* __restrict__ ws,
                                const float* __restrict__ Wout,
                                const float* __restrict__ bout,
                                float* __restrict__ out, int B)
{
    int idx = blockIdx.x * blockDim.x + threadIdx.x;
    if (idx >= B * 4) return;
    int b = idx >> 2, o = idx & 3;
    float acc = bout[o];
    const float* h = ws + (size_t)b * 32;
    const float* w = Wout + o * 32;
#pragma unroll
    for (int m = 0; m < 32; ++m) acc = fmaf(h[m], w[m], acc);
    out[idx] = acc;
}

extern "C" void kernel_launch(void* const* d_in, const int* in_sizes, int n_in,
                              void* d_out, int out_size, void* d_ws, size_t ws_size,
                              hipStream_t stream)
{
    const int B = in_sizes[0] / (T_LEN * D_IN); // 4096

    Params p;
    for (int s = 0; s < 6; ++s) {
        p.c[s].Wih = (const float*)d_in[1 + 4 * s];
        p.c[s].Whh = (const float*)d_in[2 + 4 * s];
        p.c[s].bih = (const float*)d_in[3 + 4 * s];
        p.c[s].bhh = (const float*)d_in[4 + 4 * s];
    }
    p.y = (const float*)d_in[0];
    p.hout = (float*)d_ws;

    const int waves = B * 2;               // one wave per (batch, direction)
    const int blocks = waves / 4;          // 4 waves per 256-thread block
    lstm_chain_kernel<<<blocks, 256, 0, stream>>>(p);

    const float* Wout = (const float*)d_in[25];
    const float* bout = (const float*)d_in[26];
    out_proj_kernel<<<(B * 4 + 255) / 256, 256, 0, stream>>>(
        (const float*)d_ws, Wout, bout, (float*)d_out, B);
}

// Round 2
// 640.862 us; speedup vs baseline: 1.3444x; 1.3444x over previous
//
#include <hip/hip_runtime.h>

#define T_LEN 256
#define D_IN 4
#define HID 16

struct CellW { const float *Wih, *Whh, *bih, *bhh; };
struct Params { CellW c[6]; const float* y; float* hout; };

__device__ __forceinline__ float fexp2(float x) { return __builtin_amdgcn_exp2f(x); }
__device__ __forceinline__ float frcp(float x)  { return __builtin_amdgcn_rcpf(x); }

// v_fmac_f32 with DPP row_ror:N applied to src0 (h). Weights are pre-permuted
// at init with the SAME dpp ctrl, so direction semantics are self-consistent.
#define FMAC_ROR(acc, hv, wv, N) \
    asm volatile("v_fmac_f32_dpp %0, %1, %2 row_ror:" #N " row_mask:0xf bank_mask:0xf" \
                 : "+v"(acc) : "v"(hv), "v"(wv))

// 16x16 matvec: acc += W_row(lane) . h, h distributed one value per lane of
// each 16-lane DPP row. 16 fmacs total, two accumulators to break dep chains.
// s_nop 1 guards the gfx9 "VALU write -> DPP read needs 2 wait states" hazard
// (h may have been produced immediately before; hazard recognizer can't see
// into inline asm).
__device__ __forceinline__ void matvec16(float& a0, float& a1, float h, const float (&w)[16]) {
    asm volatile("s_nop 1");
    asm volatile("v_fmac_f32 %0, %1, %2" : "+v"(a0) : "v"(h), "v"(w[0]));
    FMAC_ROR(a1, h, w[1], 1);
    FMAC_ROR(a0, h, w[2], 2);
    FMAC_ROR(a1, h, w[3], 3);
    FMAC_ROR(a0, h, w[4], 4);
    FMAC_ROR(a1, h, w[5], 5);
    FMAC_ROR(a0, h, w[6], 6);
    FMAC_ROR(a1, h, w[7], 7);
    FMAC_ROR(a0, h, w[8], 8);
    FMAC_ROR(a1, h, w[9], 9);
    FMAC_ROR(a0, h, w[10], 10);
    FMAC_ROR(a1, h, w[11], 11);
    FMAC_ROR(a0, h, w[12], 12);
    FMAC_ROR(a1, h, w[13], 13);
    FMAC_ROR(a0, h, w[14], 14);
    FMAC_ROR(a1, h, w[15], 15);
}

template<int N> __device__ __forceinline__ int ror16(int v) {
    return __builtin_amdgcn_update_dpp(0, v, 0x120 + N, 0xF, 0xF, true);
}

// pre is already scaled by -log2e (sigmoid rows) / -2log2e (g rows).
// act = rmul * 1/(1+exp2(pre)) + radd  -> sigmoid or tanh per-lane.
__device__ __forceinline__ void act_update(float pre, float rmul, float radd,
                                           int ai, int af, int ag, int ao,
                                           float& c, float& h) {
    float e = fexp2(pre);
    float s = frcp(1.f + e);
    float act = fmaf(rmul, s, radd);
    int av = __float_as_int(act);
    float gi = __int_as_float(__builtin_amdgcn_ds_bpermute(ai, av));
    float gf = __int_as_float(__builtin_amdgcn_ds_bpermute(af, av));
    float gg = __int_as_float(__builtin_amdgcn_ds_bpermute(ag, av));
    float go = __int_as_float(__builtin_amdgcn_ds_bpermute(ao, av));
    c = fmaf(gf, c, gi * gg);
    float e2 = fexp2(c * 2.8853900817779268f);            // 2*log2e*c
    float th = fmaf(-2.f, frcp(1.f + e2), 1.f);           // tanh(c)
    h = go * th;
}

__global__ void __launch_bounds__(256, 4)
lstm_chain_kernel(Params p)
{
    const int lane = threadIdx.x & 63;
    const int wid  = blockIdx.x * (blockDim.x >> 6) + (threadIdx.x >> 6);
    const int b    = wid >> 1;
    const int dir  = wid & 1;
    const int j    = lane & 15;          // hidden unit (position within DPP row)
    const int gate = lane >> 4;          // 0=i 1=f 2=g 3=o
    const int r    = lane;               // weight row == lane (torch gate order)

    const CellW c1 = p.c[dir * 3 + 0];
    const CellW c2 = p.c[dir * 3 + 1];
    const CellW c3 = p.c[dir * 3 + 2];

    // activation constants; fold kmul into weights+bias at load time
    const bool  isg  = (gate == 2);
    const float kmul = isg ? -2.8853900817779268f : -1.4426950408889634f;
    const float rmul = isg ? 2.f : 1.f;
    const float radd = isg ? -1.f : 0.f;

    // source-lane j for each row_ror:i (self-consistent with FMAC_ROR)
    int js[16];
    js[0]  = j;
    js[1]  = ror16<1>(j);  js[2]  = ror16<2>(j);  js[3]  = ror16<3>(j);
    js[4]  = ror16<4>(j);  js[5]  = ror16<5>(j);  js[6]  = ror16<6>(j);
    js[7]  = ror16<7>(j);  js[8]  = ror16<8>(j);  js[9]  = ror16<9>(j);
    js[10] = ror16<10>(j); js[11] = ror16<11>(j); js[12] = ror16<12>(j);
    js[13] = ror16<13>(j); js[14] = ror16<14>(j); js[15] = ror16<15>(j);

    // per-lane weights (84 floats), rotation-permuted, pre-scaled by kmul
    float wih1[D_IN], whh1[HID], wih2[HID], whh2[HID], wih3[HID], whh3[HID];
    {
        const float* q = c1.Wih + r * D_IN;
#pragma unroll
        for (int k = 0; k < D_IN; ++k) wih1[k] = q[k] * kmul;
    }
    {
        const float* q1 = c1.Whh + r * HID;
        const float* q2 = c2.Wih + r * HID;
        const float* q3 = c2.Whh + r * HID;
        const float* q4 = c3.Wih + r * HID;
        const float* q5 = c3.Whh + r * HID;
#pragma unroll
        for (int i = 0; i < HID; ++i) {
            const int s = js[i];
            whh1[i] = q1[s] * kmul;
            wih2[i] = q2[s] * kmul;
            whh2[i] = q3[s] * kmul;
            wih3[i] = q4[s] * kmul;
            whh3[i] = q5[s] * kmul;
        }
    }
    const float bias1 = (c1.bih[r] + c1.bhh[r]) * kmul;
    const float bias2 = (c2.bih[r] + c2.bhh[r]) * kmul;
    const float bias3 = (c3.bih[r] + c3.bhh[r]) * kmul;

    // bpermute byte-addresses for gate gather (i,f,g,o of unit j)
    const int ai = 4 * j;
    const int af = 4 * (16 + j);
    const int ag = 4 * (32 + j);
    const int ao = 4 * (48 + j);

    // state (distributed: lane holds value for unit j, replicated across rows)
    float cc1 = 0.f, cc2 = 0.f, cc3 = 0.f;
    float h1 = 0.f, h2 = 0.f, h3 = 0.f;

    const float* ybase = p.y + (size_t)b * (T_LEN * D_IN);
    const int xstep = dir ? -D_IN : D_IN;
    const float* xp = ybase + (dir ? (T_LEN - 1) * D_IN : 0);
    float4 xv = *(const float4*)xp;

#pragma unroll 1
    for (int t = 0; t < T_LEN; ++t) {
        // prefetch next x (uniform address; dummy in-range read on last iter)
        const float* xpn = (t + 1 < T_LEN) ? (xp + xstep) : ybase;
        float4 xn = *(const float4*)xpn;

        // ---- cell 1 ----
        {
            float a0 = bias1, a1 = 0.f;
            matvec16(a0, a1, h1, whh1);          // recurrence (h1 is old)
            a0 = fmaf(xv.x, wih1[0], a0);
            a1 = fmaf(xv.y, wih1[1], a1);
            a0 = fmaf(xv.z, wih1[2], a0);
            a1 = fmaf(xv.w, wih1[3], a1);
            act_update(a0 + a1, rmul, radd, ai, af, ag, ao, cc1, h1);
        }
        // ---- cell 2 ----
        {
            float a0 = bias2, a1 = 0.f;
            matvec16(a0, a1, h2, whh2);          // recurrence first (h2 old)
            matvec16(a0, a1, h1, wih2);          // input (h1 fresh; s_nop guard)
            act_update(a0 + a1, rmul, radd, ai, af, ag, ao, cc2, h2);
        }
        // ---- cell 3 ----
        {
            float a0 = bias3, a1 = 0.f;
            matvec16(a0, a1, h3, whh3);
            matvec16(a0, a1, h2, wih3);
            act_update(a0 + a1, rmul, radd, ai, af, ag, ao, cc3, h3);
        }

        xv = xn; xp = xpn;
    }

    if (lane < 16) p.hout[(size_t)b * 32 + dir * HID + j] = h3;
}

__global__ void out_proj_kernel(const float* __restrict__ ws,
                                const float* __restrict__ Wout,
                                const float* __restrict__ bout,
                                float* __restrict__ out, int B)
{
    int idx = blockIdx.x * blockDim.x + threadIdx.x;
    if (idx >= B * 4) return;
    int b = idx >> 2, o = idx & 3;
    float acc = bout[o];
    const float* h = ws + (size_t)b * 32;
    const float* w = Wout + o * 32;
#pragma unroll
    for (int m = 0; m < 32; ++m) acc = fmaf(h[m], w[m], acc);
    out[idx] = acc;
}

extern "C" void kernel_launch(void* const* d_in, const int* in_sizes, int n_in,
                              void* d_out, int out_size, void* d_ws, size_t ws_size,
                              hipStream_t stream)
{
    const int B = in_sizes[0] / (T_LEN * D_IN); // 4096

    Params p;
    for (int s = 0; s < 6; ++s) {
        p.c[s].Wih = (const float*)d_in[1 + 4 * s];
        p.c[s].Whh = (const float*)d_in[2 + 4 * s];
        p.c[s].bih = (const float*)d_in[3 + 4 * s];
        p.c[s].bhh = (const float*)d_in[4 + 4 * s];
    }
    p.y = (const float*)d_in[0];
    p.hout = (float*)d_ws;

    const int waves = B * 2;               // one wave per (batch, direction)
    const int blocks = waves / 4;          // 4 waves per 256-thread block
    lstm_chain_kernel<<<blocks, 256, 0, stream>>>(p);

    const float* Wout = (const float*)d_in[25];
    const float* bout = (const float*)d_in[26];
    out_proj_kernel<<<(B * 4 + 255) / 256, 256, 0, stream>>>(
        (const float*)d_ws, Wout, bout, (float*)d_out, B);
}